// Round 1
// baseline (296.151 us; speedup 1.0000x reference)
//
#include <hip/hip_runtime.h>
#include <hip/hip_bf16.h>

#define N_NODES 100000
#define N_FACES 200000
#define FM 32          // faces per block
#define ROWS 96        // 3 variants * FM
#define XS 168         // X row stride (shorts), 336 B: 16B-aligned, ~conflict-free
#define HS 136         // H row stride (shorts)
#define WCS 40         // W1T chunk k-stride (shorts)
#define W2S 136        // W2T k-stride (shorts)
#define NCH 5          // K chunks of 32 (K1 = 160 >= 134)

typedef __attribute__((ext_vector_type(8))) short s8v;
typedef __attribute__((ext_vector_type(4))) short s4v;
typedef __attribute__((ext_vector_type(4))) float f4v;

static __device__ __forceinline__ short f2bf(float x) {
  __hip_bfloat16 h = __float2bfloat16(x);
  short s;
  __builtin_memcpy(&s, &h, 2);
  return s;
}

// Pre-convert W1 -> bf16 W1T chunk images [kc][n(128)][WCS], with K-permutation:
// X col k in [0,128) = ff (W1 row 6+k); k in [128,134) = edges (W1 row k-128); else 0.
// Also W2 -> bf16 W2T [o(32)][W2S].
__global__ __launch_bounds__(256) void prep_kernel(
    const float* __restrict__ W1, const float* __restrict__ W2,
    short* __restrict__ w1t, short* __restrict__ w2t)
{
  int t = blockIdx.x * 256 + threadIdx.x;
  if (t < NCH * 128 * WCS) {
    int kc = t / (128 * WCS);
    int r = t % (128 * WCS);
    int n = r / WCS, kk = r % WCS;
    float v = 0.f;
    if (kk < 32) {
      int k = kc * 32 + kk;
      int gk = (k < 128) ? (k + 6) : (k < 134 ? k - 128 : -1);
      if (gk >= 0) v = W1[gk * 128 + n];
    }
    w1t[t] = f2bf(v);
  }
  if (t < 32 * W2S) {
    int o = t / W2S, k = t % W2S;
    float v = (k < 128) ? W2[k * 32 + o] : 0.f;
    w2t[t] = f2bf(v);
  }
}

__global__ __launch_bounds__(256) void face_kernel(
    const float* __restrict__ pos, const float* __restrict__ ffeat,
    const float* __restrict__ b1, const float* __restrict__ b2,
    const int* __restrict__ faces,
    const short* __restrict__ w1t_g, const short* __restrict__ w2t_g,
    float* __restrict__ out_ff, float* __restrict__ sums, int* __restrict__ cnt)
{
  __shared__ short xh[ROWS * XS];        // X [96][168]; reused as H [96][136]; then gsum f32 [96][29]
  __shared__ short wb[2][128 * WCS];     // W1T chunk double buffer
  __shared__ short w2[32 * W2S];         // W2T

  const int t = threadIdx.x;
  const int lane = t & 63;
  const int wv = t >> 6;            // wave 0..3
  const int l15 = lane & 15;
  const int lq = lane >> 4;         // 0..3
  const int kq = lq * 8;
  const int fbase = blockIdx.x * FM;

  // ---- stage W2T (bf16 copy from ws): 4352 shorts = 2176 uints
  {
    const unsigned* src = (const unsigned*)w2t_g;
    unsigned* dst = (unsigned*)w2;
#pragma unroll
    for (int i = 0; i < 9; ++i) {
      int idx = i * 256 + t;
      if (idx < (32 * W2S) / 2) dst[idx] = src[idx];
    }
  }
  // ---- stage X: ff columns (cols 0..127), triplicated across 3 variant row-groups
#pragma unroll
  for (int i = 0; i < 4; ++i) {
    int e = i * 256 + t;            // 0..1023 float4 units
    int floc = e >> 5, c4 = e & 31;
    f4v v = *(const f4v*)(ffeat + ((size_t)(fbase + floc) << 7) + (c4 << 2));
    s4v s;
    s.x = f2bf(v.x); s.y = f2bf(v.y); s.z = f2bf(v.z); s.w = f2bf(v.w);
    *(s4v*)&xh[(0 * FM + floc) * XS + (c4 << 2)] = s;
    *(s4v*)&xh[(1 * FM + floc) * XS + (c4 << 2)] = s;
    *(s4v*)&xh[(2 * FM + floc) * XS + (c4 << 2)] = s;
  }
  // ---- edges (cols 128..133) + zero pad (cols 134..167)
  if (t < ROWS) {
    int v = t >> 5, floc = t & 31, face = fbase + floc;
    int vb = (v == 2) ? 0 : v + 1;
    int vc = (v == 0) ? 2 : v - 1;
    int ia = faces[face * 3 + v];
    int ib = faces[face * 3 + vb];
    int ic = faces[face * 3 + vc];
    float ax = pos[ia * 3 + 0], ay = pos[ia * 3 + 1], az = pos[ia * 3 + 2];
    float bx = pos[ib * 3 + 0], by = pos[ib * 3 + 1], bz = pos[ib * 3 + 2];
    float cx = pos[ic * 3 + 0], cy = pos[ic * 3 + 1], cz = pos[ic * 3 + 2];
    short* xr = &xh[t * XS];
    xr[128] = f2bf(bx - ax); xr[129] = f2bf(by - ay); xr[130] = f2bf(bz - az);
    xr[131] = f2bf(cx - ax); xr[132] = f2bf(cy - ay); xr[133] = f2bf(cz - az);
#pragma unroll
    for (int c = 134; c < XS; ++c) xr[c] = 0;
  }
  // ---- stage W1T chunk 0
  const unsigned* w1u = (const unsigned*)w1t_g;
  {
    unsigned* dst = (unsigned*)wb[0];
#pragma unroll
    for (int i = 0; i < 10; ++i) dst[i * 256 + t] = w1u[i * 256 + t];
  }
  __syncthreads();

  // ---- GEMM1: (96 x 160) @ (160 x 128); wave owns N-tiles {2wv, 2wv+1}, all 6 M-tiles
  f4v acc[6][2];
#pragma unroll
  for (int m = 0; m < 6; ++m)
#pragma unroll
    for (int n = 0; n < 2; ++n) acc[m][n] = (f4v){0.f, 0.f, 0.f, 0.f};

#pragma unroll
  for (int kc = 0; kc < NCH; ++kc) {
    if (kc + 1 < NCH) {  // prefetch next chunk into other buffer
      unsigned* dst = (unsigned*)wb[(kc + 1) & 1];
      const unsigned* src = w1u + (kc + 1) * (128 * WCS / 2);
#pragma unroll
      for (int i = 0; i < 10; ++i) dst[i * 256 + t] = src[i * 256 + t];
    }
    const short* wc = wb[kc & 1];
    s8v bf0 = *(const s8v*)&wc[((wv * 2 + 0) * 16 + l15) * WCS + kq];
    s8v bf1 = *(const s8v*)&wc[((wv * 2 + 1) * 16 + l15) * WCS + kq];
#pragma unroll
    for (int m = 0; m < 6; ++m) {
      s8v af = *(const s8v*)&xh[(m * 16 + l15) * XS + kc * 32 + kq];
      acc[m][0] = __builtin_amdgcn_mfma_f32_16x16x32_bf16(af, bf0, acc[m][0], 0, 0, 0);
      acc[m][1] = __builtin_amdgcn_mfma_f32_16x16x32_bf16(af, bf1, acc[m][1], 0, 0, 0);
    }
    __syncthreads();
  }

  // ---- epilogue 1: H = relu(acc + b1) -> xh as [96][HS] bf16 (X no longer needed)
#pragma unroll
  for (int n = 0; n < 2; ++n) {
    int j = (wv * 2 + n) * 16 + l15;
    float bj = b1[j];
#pragma unroll
    for (int m = 0; m < 6; ++m) {
      int rb = m * 16 + lq * 4;
#pragma unroll
      for (int r = 0; r < 4; ++r) {
        float h = acc[m][n][r] + bj;
        xh[(rb + r) * HS + j] = f2bf(fmaxf(h, 0.f));
      }
    }
  }
  __syncthreads();

  // ---- GEMM2: (96 x 128) @ (128 x 32); 12 C-tiles, wave owns ct = 3wv..3wv+2
  f4v a2[3];
#pragma unroll
  for (int c = 0; c < 3; ++c) a2[c] = (f4v){0.f, 0.f, 0.f, 0.f};
  const int ct0 = wv * 3;
#pragma unroll
  for (int kk = 0; kk < 4; ++kk) {
    int kof = kk * 32 + kq;
#pragma unroll
    for (int c = 0; c < 3; ++c) {
      int ct = ct0 + c, mt = ct >> 1, n = ct & 1;
      s8v a = *(const s8v*)&xh[(mt * 16 + l15) * HS + kof];
      s8v b = *(const s8v*)&w2[(n * 16 + l15) * W2S + kof];
      a2[c] = __builtin_amdgcn_mfma_f32_16x16x32_bf16(a, b, a2[c], 0, 0, 0);
    }
  }
  __syncthreads();  // all H reads done before gsum overwrites the region

  // ---- epilogue 2: g = acc2 + b2; o<3 -> atomics; o>=3 -> gsum in LDS
  float* gsum = (float*)xh;
#pragma unroll
  for (int c = 0; c < 3; ++c) {
    int ct = ct0 + c, mt = ct >> 1, n = ct & 1;
    int o = n * 16 + l15;
    float bo = b2[o];
#pragma unroll
    for (int r = 0; r < 4; ++r) {
      int row = mt * 16 + lq * 4 + r;
      float g = a2[c][r] + bo;
      if (o < 3) {
        int v = row >> 5, floc = row & 31;
        int node = faces[(fbase + floc) * 3 + v];
        atomicAdd(&sums[node * 3 + o], g);
        if (o == 0) atomicAdd(&cnt[node], 1);
      } else {
        gsum[row * 29 + (o - 3)] = g;
      }
    }
  }
  __syncthreads();

  // ---- reduce over variants -> face_features_out
#pragma unroll
  for (int i = 0; i < 4; ++i) {
    int e = i * 256 + t;
    if (e < FM * 29) {
      int floc = e / 29, c = e % 29;
      float s = gsum[floc * 29 + c] + gsum[(FM + floc) * 29 + c] + gsum[(2 * FM + floc) * 29 + c];
      out_ff[(size_t)(fbase + floc) * 29 + c] = s * (1.0f / 3.0f);
    }
  }
}

__global__ __launch_bounds__(256) void node_kernel(
    const float* __restrict__ pos, const float* __restrict__ sums,
    const int* __restrict__ cnt, float* __restrict__ out)
{
  int n = blockIdx.x * 256 + threadIdx.x;
  if (n >= N_NODES) return;
  float c = fmaxf((float)cnt[n], 1.0f);
#pragma unroll
  for (int o = 0; o < 3; ++o) {
    float d = sums[n * 3 + o] / c;
    out[n * 3 + o] = d;                            // delta_pos
    out[3 * N_NODES + n * 3 + o] = pos[n * 3 + o] + d;  // new_pos
  }
}

extern "C" void kernel_launch(void* const* d_in, const int* in_sizes, int n_in,
                              void* d_out, int out_size, void* d_ws, size_t ws_size,
                              hipStream_t stream) {
  const float* pos   = (const float*)d_in[0];
  const float* ffeat = (const float*)d_in[1];
  const float* W1    = (const float*)d_in[2];
  const float* b1    = (const float*)d_in[3];
  const float* W2    = (const float*)d_in[4];
  const float* b2    = (const float*)d_in[5];
  const int*   faces = (const int*)d_in[6];
  float* out = (float*)d_out;

  float* sums = (float*)d_ws;                       // 300000 f32
  int*   cnt  = (int*)(sums + 3 * N_NODES);         // 100000 i32
  short* w1t  = (short*)(cnt + N_NODES);            // 25600 bf16
  short* w2t  = w1t + NCH * 128 * WCS;              // 4352 bf16

  hipMemsetAsync(d_ws, 0, (size_t)(3 * N_NODES + N_NODES) * 4, stream);
  prep_kernel<<<100, 256, 0, stream>>>(W1, W2, w1t, w2t);
  face_kernel<<<N_FACES / FM, 256, 0, stream>>>(pos, ffeat, b1, b2, faces, w1t, w2t,
                                                out + 6 * N_NODES, sums, cnt);
  node_kernel<<<(N_NODES + 255) / 256, 256, 0, stream>>>(pos, sums, cnt, out);
}

// Round 7
// 264.125 us; speedup vs baseline: 1.1213x; 1.1213x over previous
//
#include <hip/hip_runtime.h>
#include <hip/hip_bf16.h>

#define N_NODES 100000
#define N_FACES 200000
#define FM 32                    // faces per tile
#define ROWS 96                  // 3 variants * FM
#define NTILES (N_FACES / FM)    // 6250
#define GRID 512                 // 2 blocks/CU target
#define FS 136                   // Xff row stride (shorts)
#define ES 40                    // Xe row stride (shorts)
#define HS 136                   // H row stride (shorts)
#define W1K 160                  // w1t global k-stride
#define W2K 128                  // w2t global k-stride

typedef __attribute__((ext_vector_type(8))) short s8v;
typedef __attribute__((ext_vector_type(4))) short s4v;
typedef __attribute__((ext_vector_type(4))) float f4v;

static __device__ __forceinline__ short f2bf(float x) {
  __hip_bfloat16 h = __float2bfloat16(x);
  short s;
  __builtin_memcpy(&s, &h, 2);
  return s;
}

// W1 -> bf16 w1t[n(128)][k(160)] with K-permutation:
//   k in [0,128): ff  -> W1 row k+6 ; k in [128,134): edges -> W1 row k-128 ; else 0.
// W2 -> bf16 w2t[o(32)][k(128)].
__global__ __launch_bounds__(256) void prep_kernel(
    const float* __restrict__ W1, const float* __restrict__ W2,
    short* __restrict__ w1t, short* __restrict__ w2t)
{
  int t = blockIdx.x * 256 + threadIdx.x;
  if (t < 128 * W1K) {
    int n = t / W1K, k = t % W1K;
    float v = 0.f;
    if (k < 128) v = W1[(k + 6) * 128 + n];
    else if (k < 134) v = W1[(k - 128) * 128 + n];
    w1t[t] = f2bf(v);
  }
  if (t < 32 * W2K) {
    int o = t / W2K, k = t % W2K;
    w2t[t] = f2bf(W2[k * 32 + o]);
  }
}

__global__ __launch_bounds__(512, 4) void face_kernel(
    const float* __restrict__ pos, const float* __restrict__ ffeat,
    const float* __restrict__ b1, const float* __restrict__ b2,
    const int* __restrict__ faces,
    const short* __restrict__ w1t_g, const short* __restrict__ w2t_g,
    float* __restrict__ out_ff, float* __restrict__ sums, int* __restrict__ cnt)
{
  __shared__ short xff[2][FM * FS];     // 17408 B  (ff, shared across variants)
  __shared__ short xe[2][ROWS * ES];    // 15360 B  (edge cols, zero-padded)
  __shared__ short hbuf[ROWS * HS];     // 26112 B  (H after relu)
  __shared__ int   nidb[2][ROWS];       //   768 B  (node id per row)
  __shared__ float gsumb[FM * 30];      //  3840 B  (variant-summed g[:,3:])
  // total 63488 B <= 64 KB

  const int t = threadIdx.x;
  const int lane = t & 63;
  const int wv = t >> 6;               // 0..7
  const int l15 = lane & 15;
  const int lq = lane >> 4;            // 0..3
  const int kq = lq * 8;
  const int nsel = wv & 1;

  // ---- persistent weight fragments (registers), biases
  s8v bw1[5], bw2[4];
#pragma unroll
  for (int kc = 0; kc < 5; ++kc)
    bw1[kc] = *(const s8v*)(w1t_g + (wv * 16 + l15) * W1K + kc * 32 + kq);
#pragma unroll
  for (int kk = 0; kk < 4; ++kk)
    bw2[kk] = *(const s8v*)(w2t_g + (nsel * 16 + l15) * W2K + kk * 32 + kq);
  const float b1j = b1[wv * 16 + l15];
  const float b2o = b2[nsel * 16 + l15];

  // ---- zero xe pad cols 6..39 (both buffers, once)
  if (t < 2 * ROWS) {
    int b = t / ROWS, row = t - b * ROWS;
    s8v z = (s8v){0, 0, 0, 0, 0, 0, 0, 0};
    *(unsigned*)&xe[b][row * ES + 6] = 0u;
    *(s8v*)&xe[b][row * ES + 8] = z;
    *(s8v*)&xe[b][row * ES + 16] = z;
    *(s8v*)&xe[b][row * ES + 24] = z;
    *(s8v*)&xe[b][row * ES + 32] = z;
  }

  // ---- stage first tile into buffer 0
  {
    int fb = blockIdx.x * FM;
    const float* fp = ffeat + ((size_t)(fb + (t >> 4)) << 7) + ((t & 15) << 3);
    f4v v0 = *(const f4v*)fp, v1 = *(const f4v*)(fp + 4);
    s8v s;
    s[0] = f2bf(v0.x); s[1] = f2bf(v0.y); s[2] = f2bf(v0.z); s[3] = f2bf(v0.w);
    s[4] = f2bf(v1.x); s[5] = f2bf(v1.y); s[6] = f2bf(v1.z); s[7] = f2bf(v1.w);
    *(s8v*)&xff[0][(t >> 4) * FS + ((t & 15) << 3)] = s;
    int rt = t - 384;
    if ((unsigned)rt < 96u) {
      int face = fb + (rt & 31), v = rt >> 5;
      int i0 = faces[face * 3 + 0], i1 = faces[face * 3 + 1], i2 = faces[face * 3 + 2];
      int ia = (v == 0) ? i0 : ((v == 1) ? i1 : i2);
      int ib = (v == 0) ? i1 : ((v == 1) ? i2 : i0);
      int ic = (v == 0) ? i2 : ((v == 1) ? i0 : i1);
      float ax = pos[ia * 3], ay = pos[ia * 3 + 1], az = pos[ia * 3 + 2];
      float bx = pos[ib * 3], by = pos[ib * 3 + 1], bz = pos[ib * 3 + 2];
      float cx = pos[ic * 3], cy = pos[ic * 3 + 1], cz = pos[ic * 3 + 2];
      s4v e;
      e[0] = f2bf(bx - ax); e[1] = f2bf(by - ay); e[2] = f2bf(bz - az); e[3] = f2bf(cx - ax);
      *(s4v*)&xe[0][rt * ES] = e;
      unsigned p2 = (unsigned)(unsigned short)f2bf(cy - ay) |
                    ((unsigned)(unsigned short)f2bf(cz - az) << 16);
      *(unsigned*)&xe[0][rt * ES + 4] = p2;
      nidb[0][rt] = ia;
    }
  }
  __syncthreads();

  int iter = 0;
  for (int tile = blockIdx.x; tile < NTILES; tile += GRID, ++iter) {
    const int cur = iter & 1, nxt = cur ^ 1;
    const int fb_c = tile * FM;
    const int tile_n = tile + GRID;
    const bool hn = tile_n < NTILES;
    const int fb_n = tile_n * FM;
    const int rt = t - 384;

    // ---- issue next-tile global loads (converted/written later)
    f4v nv0, nv1;
    int ni0 = 0, ni1 = 0, ni2 = 0;
    if (hn) {
      const float* fp = ffeat + ((size_t)(fb_n + (t >> 4)) << 7) + ((t & 15) << 3);
      nv0 = *(const f4v*)fp;
      nv1 = *(const f4v*)(fp + 4);
      if ((unsigned)rt < 96u) {
        int face = fb_n + (rt & 31);
        ni0 = faces[face * 3 + 0]; ni1 = faces[face * 3 + 1]; ni2 = faces[face * 3 + 2];
      }
    }

    // ---- GEMM1: (96 x 160) @ (160 x 16-per-wave)
    f4v acc1[6];
#pragma unroll
    for (int m = 0; m < 6; ++m) acc1[m] = (f4v){0.f, 0.f, 0.f, 0.f};
    const short* xf = &xff[cur][0];
    const short* xeb = &xe[cur][0];
#pragma unroll
    for (int kc = 0; kc < 4; ++kc) {
      s8v a0 = *(const s8v*)&xf[l15 * FS + kc * 32 + kq];
      s8v a1 = *(const s8v*)&xf[(16 + l15) * FS + kc * 32 + kq];
      acc1[0] = __builtin_amdgcn_mfma_f32_16x16x32_bf16(a0, bw1[kc], acc1[0], 0, 0, 0);
      acc1[1] = __builtin_amdgcn_mfma_f32_16x16x32_bf16(a1, bw1[kc], acc1[1], 0, 0, 0);
      acc1[2] = __builtin_amdgcn_mfma_f32_16x16x32_bf16(a0, bw1[kc], acc1[2], 0, 0, 0);
      acc1[3] = __builtin_amdgcn_mfma_f32_16x16x32_bf16(a1, bw1[kc], acc1[3], 0, 0, 0);
      acc1[4] = __builtin_amdgcn_mfma_f32_16x16x32_bf16(a0, bw1[kc], acc1[4], 0, 0, 0);
      acc1[5] = __builtin_amdgcn_mfma_f32_16x16x32_bf16(a1, bw1[kc], acc1[5], 0, 0, 0);
    }
#pragma unroll
    for (int m = 0; m < 6; ++m) {
      s8v a = *(const s8v*)&xeb[(m * 16 + l15) * ES + kq];
      acc1[m] = __builtin_amdgcn_mfma_f32_16x16x32_bf16(a, bw1[4], acc1[m], 0, 0, 0);
    }

    __syncthreads();  // bar1: prev iteration's gsum reduce is complete

    // ---- epilogue 1: H = relu(acc1 + b1); zero gsumb
    {
      int j = wv * 16 + l15;
#pragma unroll
      for (int m = 0; m < 6; ++m)
#pragma unroll
        for (int r = 0; r < 4; ++r)
          hbuf[(m * 16 + lq * 4 + r) * HS + j] = f2bf(fmaxf(acc1[m][r] + b1j, 0.f));
    }
    for (int e = t; e < FM * 30; e += 512) gsumb[e] = 0.f;

    // ---- finish ff staging into xff[nxt]; issue pos gathers
    float pax = 0, pay = 0, paz = 0, pbx = 0, pby = 0, pbz = 0, pcx = 0, pcy = 0, pcz = 0;
    int ia_s = 0, ib_s = 0, ic_s = 0;
    if (hn) {
      s8v s;
      s[0] = f2bf(nv0.x); s[1] = f2bf(nv0.y); s[2] = f2bf(nv0.z); s[3] = f2bf(nv0.w);
      s[4] = f2bf(nv1.x); s[5] = f2bf(nv1.y); s[6] = f2bf(nv1.z); s[7] = f2bf(nv1.w);
      *(s8v*)&xff[nxt][(t >> 4) * FS + ((t & 15) << 3)] = s;
      if ((unsigned)rt < 96u) {
        int v = rt >> 5;
        ia_s = (v == 0) ? ni0 : ((v == 1) ? ni1 : ni2);
        ib_s = (v == 0) ? ni1 : ((v == 1) ? ni2 : ni0);
        ic_s = (v == 0) ? ni2 : ((v == 1) ? ni0 : ni1);
        pax = pos[ia_s * 3]; pay = pos[ia_s * 3 + 1]; paz = pos[ia_s * 3 + 2];
        pbx = pos[ib_s * 3]; pby = pos[ib_s * 3 + 1]; pbz = pos[ib_s * 3 + 2];
        pcx = pos[ic_s * 3]; pcy = pos[ic_s * 3 + 1]; pcz = pos[ic_s * 3 + 2];
      }
    }
    __syncthreads();  // bar2: H visible; gsumb zeroed; xff[nxt] ff written

    // ---- GEMM2 + epilogue 2 (variant-sum accumulated into gsumb via LDS atomics)
#pragma unroll
    for (int p = 0; p < 2; ++p) {
      if (p == 0 || wv < 4) {
        int m = (wv >> 1) + p * 4;
        f4v c2 = (f4v){0.f, 0.f, 0.f, 0.f};
#pragma unroll
        for (int kk = 0; kk < 4; ++kk) {
          s8v a = *(const s8v*)&hbuf[(m * 16 + l15) * HS + kk * 32 + kq];
          c2 = __builtin_amdgcn_mfma_f32_16x16x32_bf16(a, bw2[kk], c2, 0, 0, 0);
        }
        int o = nsel * 16 + l15;
#pragma unroll
        for (int r = 0; r < 4; ++r) {
          int row = m * 16 + lq * 4 + r;
          float g = c2[r] + b2o;
          if (o < 3) {
            int node = nidb[cur][row];
            atomicAdd(&sums[node * 3 + o], g);
            if (o == 0) atomicAdd(&cnt[node], 1);
          } else {
            atomicAdd(&gsumb[(row & 31) * 30 + (o - 3)], g);
          }
        }
      }
    }

    // ---- finish edge staging into xe[nxt]
    if (hn && (unsigned)rt < 96u) {
      s4v e;
      e[0] = f2bf(pbx - pax); e[1] = f2bf(pby - pay);
      e[2] = f2bf(pbz - paz); e[3] = f2bf(pcx - pax);
      *(s4v*)&xe[nxt][rt * ES] = e;
      unsigned p2 = (unsigned)(unsigned short)f2bf(pcy - pay) |
                    ((unsigned)(unsigned short)f2bf(pcz - paz) << 16);
      *(unsigned*)&xe[nxt][rt * ES + 4] = p2;
      nidb[nxt][rt] = ia_s;
    }
    __syncthreads();  // bar3: staging + gsum accumulation complete

    // ---- write face_features_out
    for (int e = t; e < FM * 29; e += 512) {
      int floc = e / 29, c = e - floc * 29;
      out_ff[((size_t)(fb_c + floc)) * 29 + c] = gsumb[floc * 30 + c] * (1.0f / 3.0f);
    }
  }
}

__global__ __launch_bounds__(256) void node_kernel(
    const float* __restrict__ pos, const float* __restrict__ sums,
    const int* __restrict__ cnt, float* __restrict__ out)
{
  int n = blockIdx.x * 256 + threadIdx.x;
  if (n >= N_NODES) return;
  float c = fmaxf((float)cnt[n], 1.0f);
#pragma unroll
  for (int o = 0; o < 3; ++o) {
    float d = sums[n * 3 + o] / c;
    out[n * 3 + o] = d;
    out[3 * N_NODES + n * 3 + o] = pos[n * 3 + o] + d;
  }
}

extern "C" void kernel_launch(void* const* d_in, const int* in_sizes, int n_in,
                              void* d_out, int out_size, void* d_ws, size_t ws_size,
                              hipStream_t stream) {
  const float* pos   = (const float*)d_in[0];
  const float* ffeat = (const float*)d_in[1];
  const float* W1    = (const float*)d_in[2];
  const float* b1    = (const float*)d_in[3];
  const float* W2    = (const float*)d_in[4];
  const float* b2    = (const float*)d_in[5];
  const int*   faces = (const int*)d_in[6];
  float* out = (float*)d_out;

  float* sums = (float*)d_ws;                  // 300000 f32
  int*   cnt  = (int*)(sums + 3 * N_NODES);    // 100000 i32
  short* w1t  = (short*)(cnt + N_NODES);       // 128*160 bf16
  short* w2t  = w1t + 128 * W1K;               // 32*128 bf16

  hipMemsetAsync(d_ws, 0, (size_t)(3 * N_NODES + N_NODES) * 4, stream);
  prep_kernel<<<80, 256, 0, stream>>>(W1, W2, w1t, w2t);
  face_kernel<<<GRID, 512, 0, stream>>>(pos, ffeat, b1, b2, faces, w1t, w2t,
                                        out + 6 * N_NODES, sums, cnt);
  node_kernel<<<(N_NODES + 255) / 256, 256, 0, stream>>>(pos, sums, cnt, out);
}